// Round 2
// baseline (277.090 us; speedup 1.0000x reference)
//
#include <hip/hip_runtime.h>
#include <hip/hip_bf16.h>
#include <math.h>

typedef __hip_bfloat16 bf16;
typedef short bf16x8 __attribute__((ext_vector_type(8)));   // 8 bf16 raw (4 VGPRs)
typedef float f32x4 __attribute__((ext_vector_type(4)));
typedef float f32x2 __attribute__((ext_vector_type(2)));

union alignas(16) Pack8 { bf16 h[8]; bf16x8 v; };

// native base-2 transcendentals (v_exp_f32 / v_log_f32 / v_rcp_f32)
#define EXP2F(x) __builtin_amdgcn_exp2f(x)
#define LOG2F(x) __builtin_amdgcn_logf(x)
#define RCPF(x)  __builtin_amdgcn_rcpf(x)

// ---------------------------------------------------------------------------
// All four weight transposes f32 -> bf16 in one dispatch.
// ---------------------------------------------------------------------------
__global__ void prep_weights(const float* __restrict__ Wa1, const float* __restrict__ Wa2,
                             const float* __restrict__ Wb1, const float* __restrict__ Wb2,
                             bf16* __restrict__ oa1, bf16* __restrict__ oa2,
                             bf16* __restrict__ ob1, bf16* __restrict__ ob2) {
    int idx = blockIdx.x * 256 + threadIdx.x;   // grid covers 393216
    if (idx < 131072) {
        int n = idx >> 9, k = idx & 511;
        oa1[idx] = __float2bfloat16(Wa1[k * 256 + n]);
    } else if (idx < 196608) {
        int i = idx - 131072; int n = i >> 8, k = i & 255;
        oa2[i] = __float2bfloat16(Wa2[k * 256 + n]);
    } else if (idx < 327680) {
        int i = idx - 196608; int n = i >> 9, k = i & 511;
        ob1[i] = __float2bfloat16(Wb1[k * 256 + n]);
    } else {
        int i = idx - 327680; int n = i >> 8, k = i & 255;
        ob2[i] = __float2bfloat16(Wb2[k * 256 + n]);
    }
}

// ---------------------------------------------------------------------------
// Fused 2-layer MLP, BARRIER-FREE GEMMs: operand fragments load straight from
// global (L2/L3-resident: X 33 MB f32, W 0.75 MB bf16). LDS only holds h for
// the layer-1 -> layer-2 cross-wave redistribution (one barrier total).
// Tile 32 rows x 256 cols, 4 waves (each 32x64). grid (256,1,4).
// ---------------------------------------------------------------------------
__global__ __launch_bounds__(256, 4)
void mlp_fused(const float* __restrict__ q, const float* __restrict__ k,
               const bf16* __restrict__ Wa1t, const bf16* __restrict__ Wa2t,
               const bf16* __restrict__ Wb1t, const bf16* __restrict__ Wb2t,
               bf16* __restrict__ qa, bf16* __restrict__ ka,
               bf16* __restrict__ qb, bf16* __restrict__ kb) {
    const int z = blockIdx.z;
    const float* X  = (z & 1) ? k : q;
    const bf16*  W1 = (z >> 1) ? Wb1t : Wa1t;
    const bf16*  W2 = (z >> 1) ? Wb2t : Wa2t;
    bf16* Y = (z == 0) ? qa : (z == 1) ? ka : (z == 2) ? qb : kb;
    const int m0 = blockIdx.x * 32;

    __shared__ short lH[32 * 264];    // h: 32 rows x 256 cols (+8 pad)

    const int tid  = threadIdx.x;
    const int wave = tid >> 6, lane = tid & 63;
    const int wn = wave * 64;
    const int quad = lane >> 4, r16 = lane & 15;

    // ---- layer 1: K = 512. A = X rows (f32, convert in-register); B = W1 rows.
    {
        f32x4 acc[2][4] = {};
        const float* xr0 = X + (size_t)(m0 + r16) * 512 + quad * 8;
        const float* xr1 = xr0 + 16 * 512;
        const bf16*  wr0 = W1 + (size_t)(wn + r16) * 512 + quad * 8;
#pragma unroll
        for (int kk = 0; kk < 512; kk += 32) {
            bf16x8 af[2], bfr[4];
#pragma unroll
            for (int f = 0; f < 2; f++) {
                const float* p = (f ? xr1 : xr0) + kk;
                Pack8 u;
#pragma unroll
                for (int j = 0; j < 8; j++) u.h[j] = __float2bfloat16(p[j]);
                af[f] = u.v;
            }
#pragma unroll
            for (int f = 0; f < 4; f++)
                bfr[f] = *(const bf16x8*)(wr0 + (size_t)f * 16 * 512 + kk);
#pragma unroll
            for (int i = 0; i < 2; i++)
#pragma unroll
                for (int j = 0; j < 4; j++)
                    acc[i][j] = __builtin_amdgcn_mfma_f32_16x16x32_bf16(
                        af[i], bfr[j], acc[i][j], 0, 0, 0);
        }
        // h -> LDS (relu, bf16); local row = i*16+quad*4+r, col = wn+j*16+r16
#pragma unroll
        for (int i = 0; i < 2; i++)
#pragma unroll
            for (int j = 0; j < 4; j++)
#pragma unroll
                for (int r = 0; r < 4; r++) {
                    float v = acc[i][j][r];
                    v = v > 0.f ? v : 0.f;
                    ((bf16*)lH)[(i * 16 + quad * 4 + r) * 264 + wn + j * 16 + r16] =
                        __float2bfloat16(v);
                }
    }
    __syncthreads();

    // ---- layer 2: K = 256, A from lH, B = W2 rows direct from global.
    f32x4 acc2[2][4] = {};
    {
        const bf16* wr0 = W2 + (size_t)(wn + r16) * 256 + quad * 8;
#pragma unroll
        for (int kk = 0; kk < 256; kk += 32) {
            bf16x8 af[2], bfr[4];
#pragma unroll
            for (int f = 0; f < 2; f++)
                af[f] = *(const bf16x8*)&lH[(f * 16 + r16) * 264 + kk + quad * 8];
#pragma unroll
            for (int f = 0; f < 4; f++)
                bfr[f] = *(const bf16x8*)(wr0 + (size_t)f * 16 * 256 + kk);
#pragma unroll
            for (int i = 0; i < 2; i++)
#pragma unroll
                for (int j = 0; j < 4; j++)
                    acc2[i][j] = __builtin_amdgcn_mfma_f32_16x16x32_bf16(
                        af[i], bfr[j], acc2[i][j], 0, 0, 0);
        }
    }

#pragma unroll
    for (int i = 0; i < 2; i++) {
        int rbase = m0 + i * 16 + quad * 4;
#pragma unroll
        for (int j = 0; j < 4; j++) {
            int col = wn + j * 16 + r16;
#pragma unroll
            for (int r = 0; r < 4; r++) {
                float v = acc2[i][j][r];
                v = v > 0.f ? v : 0.f;
                Y[(size_t)(rbase + r) * 256 + col] = __float2bfloat16(v);
            }
        }
    }
}

// ---------------------------------------------------------------------------
// Packed f32x2 helpers (v_pk_fma_f32 / v_pk_mul_f32 / v_pk_add_f32).
// ---------------------------------------------------------------------------
__device__ __forceinline__ f32x2 vexp2(f32x2 x) {
    f32x2 r; r.x = EXP2F(x.x); r.y = EXP2F(x.y); return r;
}
__device__ __forceinline__ f32x2 vlog2(f32x2 x) {
    f32x2 r; r.x = LOG2F(x.x); r.y = LOG2F(x.y); return r;
}
__device__ __forceinline__ f32x2 vrcp(f32x2 x) {
    f32x2 r; r.x = RCPF(x.x); r.y = RCPF(x.y); return r;
}
__device__ __forceinline__ f32x2 vclamp(f32x2 x, float lo, float hi) {
    f32x2 r;
    r.x = fminf(fmaxf(x.x, lo), hi);
    r.y = fminf(fmaxf(x.y, lo), hi);
    return r;
}

// HardKuma on an element PAIR. All work in log2 units. (See round-1 notes:
// Stirling shift-2, shared v_rcp for the three corrections, softplus kept
// in log2 domain.)
__device__ __forceinline__ f32x2 hardkuma2(f32x2 la, f32x2 lb) {
    const float LOG2E = 1.44269504f;
    f32x2 lw = vlog2(1.f + vexp2(la * LOG2E));
    f32x2 lv = vlog2(1.f + vexp2(lb * LOG2E));
    lw = vclamp(lw, 0.01442695f, 144.269504f);   // a in [0.01,100]
    lv = vclamp(lv, 0.01442695f, 144.269504f);
    f32x2 b = 0.69314718f * lv;

    // discrete-mass path
    f32x2 t0a = vexp2(-2.48490665f * lw);        // 12^{-a}
    f32x2 t1a = vexp2(-0.08701138f * lw);        // (12/11)^{-a}
    f32x2 q0 = vexp2(b * vlog2(1.f - t0a));      // (1-t0^a)^b = 1 - p0
    f32x2 p1 = vexp2(b * vlog2(1.f - t1a));      // P(h=1)
    f32x2 pc = q0 - p1;
    f32x2 p0 = 1.f - q0;

    // mean path: g = 1 + 1/a = 1 + log2e/lw
    f32x2 g  = 1.44269504f * vrcp(lw) + 1.f;
    f32x2 gb = g + b;
    f32x2 g2 = g + 2.f, b2 = b + 2.f, gb2 = gb + 2.f;

    f32x2 s = (g + 1.5f) * vlog2(g2) + (b + 1.5f) * vlog2(b2)
            - (gb + 1.5f) * vlog2(gb2);

    const float C1 = 0.12022459f;                // log2e/12
    const float C2 = -0.00400749f;               // -log2e/360
    f32x2 pg  = g2 * b2;
    f32x2 rr3 = vrcp(pg * gb2);
    f32x2 ig  = rr3 * (b2 * gb2);
    f32x2 ib  = rr3 * (g2 * gb2);
    f32x2 igb = rr3 * pg;
    f32x2 corr = ig  * (C1 + C2 * (ig  * ig))
               + ib  * (C1 + C2 * (ib  * ib))
               - igb * (C1 + C2 * (igb * igb));
    s += corr - 1.55964202f;                     // 0.5*log2(2pi) - 2*log2e

    f32x2 ng = g * (g + 1.f), nb = b * (b + 1.f), ngb = gb * (gb + 1.f);
    s += vlog2(ngb * vrcp(ng * nb));

    f32x2 mean = (1.2f * b) * vexp2(s) - 0.1f;   // L + (R-L)*b*Beta
    mean = vclamp(mean, 0.f, 1.f);

    f32x2 att;
    att.x = (pc.x < 0.5f) ? ((p0.x > p1.x) ? 0.f : 1.f) : mean.x;
    att.y = (pc.y < 0.5f) ? ((p0.y > p1.y) ? 0.f : 1.f) : mean.y;
    return att;
}

// ---------------------------------------------------------------------------
// Fused score GEMMs + HardKuma epilogue, BARRIER-FREE: fragments load direct
// from global (inputs are 16.8 MB total -> L2/L3-resident; each dwordx4 load
// covers 16 rows x 64 B = full cache lines). No LDS staging, no phase-lock:
// epilogue VALU of one wave overlaps loads/MFMA of others.
// Tile 128(t) x 64(s); 4 waves of 64x32; grid (16, 32, 4).
// ---------------------------------------------------------------------------
__global__ __launch_bounds__(256, 3)
void kuma_attn(const bf16* __restrict__ qa, const bf16* __restrict__ ka,
               const bf16* __restrict__ qb, const bf16* __restrict__ kb,
               const float* __restrict__ dist_emb, float* __restrict__ out) {
    const int bidx = blockIdx.z;
    const int t0 = blockIdx.x * 128;
    const int s0 = blockIdx.y * 64;

    __shared__ float sDist[23];
    const int tid = threadIdx.x;
    if (tid < 23) sDist[tid] = dist_emb[tid];
    __syncthreads();

    const int wave = tid >> 6, lane = tid & 63;
    const int wm = (wave >> 1) * 64, wn = (wave & 1) * 32;
    const int quad = lane >> 4, r16 = lane & 15;
    const size_t base = (size_t)bidx * 2048 * 256;

    // per-lane base addresses (row stride 256 bf16 = 512 B)
    const size_t aoff = base + (size_t)(t0 + wm + r16) * 256 + quad * 8;
    const size_t boff = base + (size_t)(s0 + wn + r16) * 256 + quad * 8;

    f32x4 accA[4][2] = {};
    f32x4 accB[4][2] = {};

#pragma unroll
    for (int kk = 0; kk < 256; kk += 32) {
        bf16x8 aA[4], aB[4], bA[2], bB[2];
#pragma unroll
        for (int f = 0; f < 4; f++) {
            size_t o = aoff + (size_t)f * 16 * 256 + kk;
            aA[f] = *(const bf16x8*)(qa + o);
            aB[f] = *(const bf16x8*)(qb + o);
        }
#pragma unroll
        for (int f = 0; f < 2; f++) {
            size_t o = boff + (size_t)f * 16 * 256 + kk;
            bA[f] = *(const bf16x8*)(ka + o);
            bB[f] = *(const bf16x8*)(kb + o);
        }
#pragma unroll
        for (int i = 0; i < 4; i++)
#pragma unroll
            for (int j = 0; j < 2; j++) {
                accA[i][j] = __builtin_amdgcn_mfma_f32_16x16x32_bf16(
                    aA[i], bA[j], accA[i][j], 0, 0, 0);
                accB[i][j] = __builtin_amdgcn_mfma_f32_16x16x32_bf16(
                    aB[i], bB[j], accB[i][j], 0, 0, 0);
            }
    }

    // Epilogue: rows in PAIRS so the HardKuma polynomial math packs to v_pk_*.
#pragma unroll
    for (int i = 0; i < 4; i++) {
#pragma unroll
        for (int j = 0; j < 2; j++) {
            int s = s0 + wn + j * 16 + r16;
#pragma unroll
            for (int rr = 0; rr < 2; rr++) {
                int t = t0 + wm + i * 16 + quad * 4 + rr * 2;
                int d0 = s - t;
                int d1 = d0 - 1;
                d0 = d0 < -11 ? -11 : (d0 > 11 ? 11 : d0);
                d1 = d1 < -11 ? -11 : (d1 > 11 ? 11 : d1);
                float rd0 = sDist[d0 + 11];
                float rd1 = sDist[d1 + 11];
                f32x2 la = { accA[i][j][rr * 2] + rd0, accA[i][j][rr * 2 + 1] + rd1 };
                f32x2 lbv = { accB[i][j][rr * 2] + rd0, accB[i][j][rr * 2 + 1] + rd1 };
                f32x2 att = hardkuma2(la, lbv);
                out[((size_t)bidx * 2048 + t) * 2048 + s] = att.x;
                out[((size_t)bidx * 2048 + t + 1) * 2048 + s] = att.y;
            }
        }
    }
}

// ---------------------------------------------------------------------------
extern "C" void kernel_launch(void* const* d_in, const int* in_sizes, int n_in,
                              void* d_out, int out_size, void* d_ws, size_t ws_size,
                              hipStream_t stream) {
    const float* q    = (const float*)d_in[0];
    const float* k    = (const float*)d_in[1];
    const float* Wa1  = (const float*)d_in[2];
    const float* Wa2  = (const float*)d_in[4];
    const float* Wb1  = (const float*)d_in[6];
    const float* Wb2  = (const float*)d_in[8];
    const float* dist = (const float*)d_in[10];
    float* out = (float*)d_out;

    bf16* wsbf = (bf16*)d_ws;
    bf16* Wa1t = wsbf;                 // 512*256
    bf16* Wa2t = Wa1t + 131072;        // 256*256
    bf16* Wb1t = Wa2t + 65536;
    bf16* Wb2t = Wb1t + 131072;
    bf16* qa   = Wb2t + 65536;         // 8192*256 each
    bf16* ka   = qa + 2097152;
    bf16* qb   = ka + 2097152;
    bf16* kb   = qb + 2097152;
    // total ws ~17.6 MB

    prep_weights<<<1536, 256, 0, stream>>>(Wa1, Wa2, Wb1, Wb2,
                                           Wa1t, Wa2t, Wb1t, Wb2t);

    dim3 g1(256, 1, 4), blk(256, 1, 1);
    mlp_fused<<<g1, blk, 0, stream>>>(q, k, Wa1t, Wa2t, Wb1t, Wb2t,
                                      qa, ka, qb, kb);

    dim3 g2(16, 32, 4);
    kuma_attn<<<g2, blk, 0, stream>>>(qa, ka, qb, kb, dist, out);
}

// Round 3
// 201.304 us; speedup vs baseline: 1.3765x; 1.3765x over previous
//
#include <hip/hip_runtime.h>
#include <hip/hip_bf16.h>
#include <math.h>

typedef __hip_bfloat16 bf16;
typedef short bf16x8 __attribute__((ext_vector_type(8)));   // 8 bf16 raw (4 VGPRs)
typedef float f32x4 __attribute__((ext_vector_type(4)));
typedef float f32x2 __attribute__((ext_vector_type(2)));

union alignas(16) Pack8 { bf16 h[8]; bf16x8 v; };

// native base-2 transcendentals (v_exp_f32 / v_log_f32 / v_rcp_f32)
#define EXP2F(x) __builtin_amdgcn_exp2f(x)
#define LOG2F(x) __builtin_amdgcn_logf(x)
#define RCPF(x)  __builtin_amdgcn_rcpf(x)

// Mean-table box: for scores in [TAB_LO, TAB_HI] (a,b in [0.533,1.502]),
// pc >= 0.596 always (corner-verified; pc unimodal in each var), so the
// output is ALWAYS the continuous mean there -> bilinear table lookup.
#define TAB_N   64
#define TAB_LO  (-0.35f)
#define TAB_HI  (1.25f)

// ---------------------------------------------------------------------------
// All four weight transposes f32 -> bf16 in one dispatch.
// ---------------------------------------------------------------------------
__global__ void prep_weights(const float* __restrict__ Wa1, const float* __restrict__ Wa2,
                             const float* __restrict__ Wb1, const float* __restrict__ Wb2,
                             bf16* __restrict__ oa1, bf16* __restrict__ oa2,
                             bf16* __restrict__ ob1, bf16* __restrict__ ob2) {
    int idx = blockIdx.x * 256 + threadIdx.x;   // grid covers 393216
    if (idx < 131072) {
        int n = idx >> 9, k = idx & 511;
        oa1[idx] = __float2bfloat16(Wa1[k * 256 + n]);
    } else if (idx < 196608) {
        int i = idx - 131072; int n = i >> 8, k = i & 255;
        oa2[i] = __float2bfloat16(Wa2[k * 256 + n]);
    } else if (idx < 327680) {
        int i = idx - 196608; int n = i >> 9, k = i & 511;
        ob1[i] = __float2bfloat16(Wb1[k * 256 + n]);
    } else {
        int i = idx - 327680; int n = i >> 8, k = i & 255;
        ob2[i] = __float2bfloat16(Wb2[k * 256 + n]);
    }
}

// ---------------------------------------------------------------------------
// Exact f64 mean-table generator (runs AFTER mlp_fused; writes into the
// then-dead Wa1t workspace region). 64x64 entries over the score box.
// ---------------------------------------------------------------------------
__device__ double lgam_d(double z) {
    double s = 0.0;
    while (z < 8.0) { s -= log(z); z += 1.0; }
    double iz = 1.0 / z, iz2 = iz * iz;
    return s + (z - 0.5) * log(z) - z + 0.91893853320467274
         + iz * (8.3333333333333333e-2 + iz2 * (-2.7777777777777778e-3
         + iz2 * 7.9365079365079365e-4));
}

__global__ void gen_table(float* __restrict__ tab) {
    int idx = blockIdx.x * 256 + threadIdx.x;
    if (idx >= TAB_N * TAB_N) return;
    int ia = idx >> 6, ib = idx & 63;
    double step = ((double)TAB_HI - (double)TAB_LO) / (TAB_N - 1);
    double sa = (double)TAB_LO + ia * step;
    double sb = (double)TAB_LO + ib * step;
    double a = log(1.0 + exp(sa));
    double b = log(1.0 + exp(sb));
    a = fmin(fmax(a, 0.01), 100.0);
    b = fmin(fmax(b, 0.01), 100.0);
    double g = 1.0 + 1.0 / a;
    double lbeta = lgam_d(g) + lgam_d(b) - lgam_d(g + b);
    double mean = -0.1 + 1.2 * (b * exp(lbeta));
    mean = fmin(fmax(mean, 0.0), 1.0);
    tab[idx] = (float)mean;
}

// ---------------------------------------------------------------------------
// Fused 2-layer MLP (round-1 form: LDS-staged, 64 rows/block, 2 barriers/kk).
// ---------------------------------------------------------------------------
__global__ __launch_bounds__(256, 2)
void mlp_fused(const float* __restrict__ q, const float* __restrict__ k,
               const bf16* __restrict__ Wa1t, const bf16* __restrict__ Wa2t,
               const bf16* __restrict__ Wb1t, const bf16* __restrict__ Wb2t,
               bf16* __restrict__ qa, bf16* __restrict__ ka,
               bf16* __restrict__ qb, bf16* __restrict__ kb) {
    const int z = blockIdx.z;
    const float* X  = (z & 1) ? k : q;
    const bf16*  W1 = (z >> 1) ? Wb1t : Wa1t;
    const bf16*  W2 = (z >> 1) ? Wb2t : Wa2t;
    bf16* Y = (z == 0) ? qa : (z == 1) ? ka : (z == 2) ? qb : kb;
    const int m0 = blockIdx.x * 64;

    __shared__ short lA[64 * 40];     // layer-1 A tile
    __shared__ short lB[256 * 40];    // W staging (both layers)
    __shared__ short lH[64 * 264];    // h: 64 rows x 256 cols (+8 pad)

    const int tid  = threadIdx.x;
    const int wave = tid >> 6, lane = tid & 63;
    const int wn = wave * 64;
    const int quad = lane >> 4, r16 = lane & 15;

    // ---- layer 1: K = 512, X is f32 (convert during staging)
    {
        f32x4 acc[4][4] = {};
        for (int kk = 0; kk < 512; kk += 32) {
            {
                int r = tid >> 2, c = (tid & 3) * 8;
                const float* p = X + (size_t)(m0 + r) * 512 + kk + c;
                Pack8 u;
#pragma unroll
                for (int j = 0; j < 8; j++) u.h[j] = __float2bfloat16(p[j]);
                *(bf16x8*)&lA[r * 40 + c] = u.v;
            }
            for (int i = tid; i < 1024; i += 256) {
                int r = i >> 2, c = (i & 3) * 8;
                *(bf16x8*)&lB[r * 40 + c] =
                    *(const bf16x8*)(W1 + (size_t)r * 512 + kk + c);
            }
            __syncthreads();
            bf16x8 af[4], bfr[4];
#pragma unroll
            for (int f = 0; f < 4; f++) {
                af[f]  = *(const bf16x8*)&lA[(f * 16 + r16) * 40 + quad * 8];
                bfr[f] = *(const bf16x8*)&lB[(wn + f * 16 + r16) * 40 + quad * 8];
            }
#pragma unroll
            for (int i = 0; i < 4; i++)
#pragma unroll
                for (int j = 0; j < 4; j++)
                    acc[i][j] = __builtin_amdgcn_mfma_f32_16x16x32_bf16(
                        af[i], bfr[j], acc[i][j], 0, 0, 0);
            __syncthreads();
        }
#pragma unroll
        for (int i = 0; i < 4; i++)
#pragma unroll
            for (int j = 0; j < 4; j++)
#pragma unroll
                for (int r = 0; r < 4; r++) {
                    float v = acc[i][j][r];
                    v = v > 0.f ? v : 0.f;
                    ((bf16*)lH)[(i * 16 + quad * 4 + r) * 264 + wn + j * 16 + r16] =
                        __float2bfloat16(v);
                }
    }
    __syncthreads();

    // ---- layer 2: K = 256, A comes from lH
    f32x4 acc2[4][4] = {};
    for (int kk = 0; kk < 256; kk += 32) {
        for (int i = tid; i < 1024; i += 256) {
            int r = i >> 2, c = (i & 3) * 8;
            *(bf16x8*)&lB[r * 40 + c] =
                *(const bf16x8*)(W2 + (size_t)r * 256 + kk + c);
        }
        __syncthreads();
        bf16x8 af[4], bfr[4];
#pragma unroll
        for (int f = 0; f < 4; f++) {
            af[f]  = *(const bf16x8*)&lH[(f * 16 + r16) * 264 + kk + quad * 8];
            bfr[f] = *(const bf16x8*)&lB[(wn + f * 16 + r16) * 40 + quad * 8];
        }
#pragma unroll
        for (int i = 0; i < 4; i++)
#pragma unroll
            for (int j = 0; j < 4; j++)
                acc2[i][j] = __builtin_amdgcn_mfma_f32_16x16x32_bf16(
                    af[i], bfr[j], acc2[i][j], 0, 0, 0);
        __syncthreads();
    }

#pragma unroll
    for (int i = 0; i < 4; i++) {
        int rbase = m0 + i * 16 + quad * 4;
#pragma unroll
        for (int j = 0; j < 4; j++) {
            int col = wn + j * 16 + r16;
#pragma unroll
            for (int r = 0; r < 4; r++) {
                float v = acc2[i][j][r];
                v = v > 0.f ? v : 0.f;
                Y[(size_t)(rbase + r) * 256 + col] = __float2bfloat16(v);
            }
        }
    }
}

// ---------------------------------------------------------------------------
// Packed f32x2 helpers.
// ---------------------------------------------------------------------------
__device__ __forceinline__ f32x2 vexp2(f32x2 x) {
    f32x2 r; r.x = EXP2F(x.x); r.y = EXP2F(x.y); return r;
}
__device__ __forceinline__ f32x2 vlog2(f32x2 x) {
    f32x2 r; r.x = LOG2F(x.x); r.y = LOG2F(x.y); return r;
}
__device__ __forceinline__ f32x2 vrcp(f32x2 x) {
    f32x2 r; r.x = RCPF(x.x); r.y = RCPF(x.y); return r;
}
__device__ __forceinline__ f32x2 vclamp(f32x2 x, float lo, float hi) {
    f32x2 r;
    r.x = fminf(fmaxf(x.x, lo), hi);
    r.y = fminf(fmaxf(x.y, lo), hi);
    return r;
}

// Exact HardKuma pair (round-1 validated). COLD fallback path only.
__device__ __noinline__ f32x2 hardkuma_slow(f32x2 la, f32x2 lb) {
    const float LOG2E = 1.44269504f;
    f32x2 lw = vlog2(1.f + vexp2(la * LOG2E));
    f32x2 lv = vlog2(1.f + vexp2(lb * LOG2E));
    lw = vclamp(lw, 0.01442695f, 144.269504f);   // a in [0.01,100]
    lv = vclamp(lv, 0.01442695f, 144.269504f);
    f32x2 b = 0.69314718f * lv;

    f32x2 t0a = vexp2(-2.48490665f * lw);        // 12^{-a}
    f32x2 t1a = vexp2(-0.08701138f * lw);        // (12/11)^{-a}
    f32x2 q0 = vexp2(b * vlog2(1.f - t0a));      // 1 - p0
    f32x2 p1 = vexp2(b * vlog2(1.f - t1a));      // P(h=1)
    f32x2 pc = q0 - p1;
    f32x2 p0 = 1.f - q0;

    f32x2 g  = 1.44269504f * vrcp(lw) + 1.f;
    f32x2 gb = g + b;
    f32x2 g2 = g + 2.f, b2 = b + 2.f, gb2 = gb + 2.f;

    f32x2 s = (g + 1.5f) * vlog2(g2) + (b + 1.5f) * vlog2(b2)
            - (gb + 1.5f) * vlog2(gb2);

    const float C1 = 0.12022459f;                // log2e/12
    const float C2 = -0.00400749f;               // -log2e/360
    f32x2 pg  = g2 * b2;
    f32x2 rr3 = vrcp(pg * gb2);
    f32x2 ig  = rr3 * (b2 * gb2);
    f32x2 ib  = rr3 * (g2 * gb2);
    f32x2 igb = rr3 * pg;
    f32x2 corr = ig  * (C1 + C2 * (ig  * ig))
               + ib  * (C1 + C2 * (ib  * ib))
               - igb * (C1 + C2 * (igb * igb));
    s += corr - 1.55964202f;                     // 0.5*log2(2pi) - 2*log2e

    f32x2 ng = g * (g + 1.f), nb = b * (b + 1.f), ngb = gb * (gb + 1.f);
    s += vlog2(ngb * vrcp(ng * nb));

    f32x2 mean = (1.2f * b) * vexp2(s) - 0.1f;
    mean = vclamp(mean, 0.f, 1.f);

    f32x2 att;
    att.x = (pc.x < 0.5f) ? ((p0.x > p1.x) ? 0.f : 1.f) : mean.x;
    att.y = (pc.y < 0.5f) ? ((p0.y > p1.y) ? 0.f : 1.f) : mean.y;
    return att;
}

// ---------------------------------------------------------------------------
// Fused score GEMMs + table-lookup HardKuma epilogue.
// Tile 128(t) x 64(s); 4 waves of 64x32; grid (16, 32, 4).
// ---------------------------------------------------------------------------
__global__ __launch_bounds__(256, 2)
void kuma_attn(const bf16* __restrict__ qa, const bf16* __restrict__ ka,
               const bf16* __restrict__ qb, const bf16* __restrict__ kb,
               const float* __restrict__ dist_emb, const float* __restrict__ tabg,
               float* __restrict__ out) {
    const int bidx = blockIdx.z;
    const int t0 = blockIdx.x * 128;
    const int s0 = blockIdx.y * 64;

    __shared__ short lQa[128 * 40], lQb[128 * 40];
    __shared__ short lKa[64 * 40],  lKb[64 * 40];
    __shared__ float sDist[23];
    __shared__ float sTab[TAB_N * TAB_N];        // 16 KB mean table

    const int tid = threadIdx.x;
    if (tid < 23) sDist[tid] = dist_emb[tid];
    for (int i = tid; i < (TAB_N * TAB_N) / 4; i += 256)
        ((f32x4*)sTab)[i] = ((const f32x4*)tabg)[i];
    // first k-loop barrier covers sDist/sTab visibility (used only in epilogue)

    const int wave = tid >> 6, lane = tid & 63;
    const int wm = (wave >> 1) * 64, wn = (wave & 1) * 32;
    const int quad = lane >> 4, r16 = lane & 15;
    const size_t base = (size_t)bidx * 2048 * 256;

    f32x4 accA[4][2] = {};
    f32x4 accB[4][2] = {};

    for (int kk = 0; kk < 256; kk += 32) {
        {
            int r = tid >> 2, c = (tid & 3) * 8;
            size_t gq = base + (size_t)(t0 + r) * 256 + kk + c;
            *(bf16x8*)&lQa[r * 40 + c] = *(const bf16x8*)(qa + gq);
            *(bf16x8*)&lQb[r * 40 + c] = *(const bf16x8*)(qb + gq);
            int i2 = tid + 256;
            int r2 = i2 >> 2, c2 = (i2 & 3) * 8;
            size_t gq2 = base + (size_t)(t0 + r2) * 256 + kk + c2;
            *(bf16x8*)&lQa[r2 * 40 + c2] = *(const bf16x8*)(qa + gq2);
            *(bf16x8*)&lQb[r2 * 40 + c2] = *(const bf16x8*)(qb + gq2);
            size_t gk = base + (size_t)(s0 + r) * 256 + kk + c;
            *(bf16x8*)&lKa[r * 40 + c] = *(const bf16x8*)(ka + gk);
            *(bf16x8*)&lKb[r * 40 + c] = *(const bf16x8*)(kb + gk);
        }
        __syncthreads();
        bf16x8 aA[4], aB[4], bA[2], bB[2];
#pragma unroll
        for (int f = 0; f < 4; f++) {
            int ar = (wm + f * 16 + r16) * 40 + quad * 8;
            aA[f] = *(const bf16x8*)&lQa[ar];
            aB[f] = *(const bf16x8*)&lQb[ar];
        }
#pragma unroll
        for (int f = 0; f < 2; f++) {
            int br = (wn + f * 16 + r16) * 40 + quad * 8;
            bA[f] = *(const bf16x8*)&lKa[br];
            bB[f] = *(const bf16x8*)&lKb[br];
        }
#pragma unroll
        for (int i = 0; i < 4; i++)
#pragma unroll
            for (int j = 0; j < 2; j++) {
                accA[i][j] = __builtin_amdgcn_mfma_f32_16x16x32_bf16(
                    aA[i], bA[j], accA[i][j], 0, 0, 0);
                accB[i][j] = __builtin_amdgcn_mfma_f32_16x16x32_bf16(
                    aB[i], bB[j], accB[i][j], 0, 0, 0);
            }
        __syncthreads();
    }

    // Epilogue: bilinear mean-table lookup (zero transcendentals in-box);
    // __any-guarded exact fallback for out-of-box lanes.
    const float SCALE = (TAB_N - 1) / (TAB_HI - TAB_LO);   // 39.375
#pragma unroll
    for (int i = 0; i < 4; i++) {
#pragma unroll
        for (int j = 0; j < 2; j++) {
            int s = s0 + wn + j * 16 + r16;
#pragma unroll
            for (int rr = 0; rr < 2; rr++) {
                int t = t0 + wm + i * 16 + quad * 4 + rr * 2;
                int d0 = s - t;
                int d1 = d0 - 1;
                d0 = d0 < -11 ? -11 : (d0 > 11 ? 11 : d0);
                d1 = d1 < -11 ? -11 : (d1 > 11 ? 11 : d1);
                float rd0 = sDist[d0 + 11];
                float rd1 = sDist[d1 + 11];
                f32x2 la  = { accA[i][j][rr * 2] + rd0, accA[i][j][rr * 2 + 1] + rd1 };
                f32x2 lbv = { accB[i][j][rr * 2] + rd0, accB[i][j][rr * 2 + 1] + rd1 };

                float mn = fminf(fminf(la.x, la.y), fminf(lbv.x, lbv.y));
                float mx = fmaxf(fmaxf(la.x, la.y), fmaxf(lbv.x, lbv.y));

                f32x2 u = vclamp((la  - TAB_LO) * SCALE, 0.f, (float)(TAB_N - 1));
                f32x2 v = vclamp((lbv - TAB_LO) * SCALE, 0.f, (float)(TAB_N - 1));
                int ia0 = (int)u.x; ia0 = ia0 > TAB_N - 2 ? TAB_N - 2 : ia0;
                int ia1 = (int)u.y; ia1 = ia1 > TAB_N - 2 ? TAB_N - 2 : ia1;
                int ib0 = (int)v.x; ib0 = ib0 > TAB_N - 2 ? TAB_N - 2 : ib0;
                int ib1 = (int)v.y; ib1 = ib1 > TAB_N - 2 ? TAB_N - 2 : ib1;
                f32x2 fa = { u.x - (float)ia0, u.y - (float)ia1 };
                f32x2 fb = { v.x - (float)ib0, v.y - (float)ib1 };
                const float* tp0 = sTab + (ia0 << 6) + ib0;
                const float* tp1 = sTab + (ia1 << 6) + ib1;
                f32x2 t00 = { tp0[0],         tp1[0]         };
                f32x2 t01 = { tp0[1],         tp1[1]         };
                f32x2 t10 = { tp0[TAB_N],     tp1[TAB_N]     };
                f32x2 t11 = { tp0[TAB_N + 1], tp1[TAB_N + 1] };
                f32x2 m0 = t00 + fb * (t01 - t00);
                f32x2 m1 = t10 + fb * (t11 - t10);
                f32x2 att = m0 + fa * (m1 - m0);

                bool oob = (mn < TAB_LO) | (mx > TAB_HI);
                if (__builtin_expect(__any(oob), 0)) {
                    f32x2 ex = hardkuma_slow(la, lbv);
                    if (oob) att = ex;
                }

                out[((size_t)bidx * 2048 + t) * 2048 + s] = att.x;
                out[((size_t)bidx * 2048 + t + 1) * 2048 + s] = att.y;
            }
        }
    }
}

// ---------------------------------------------------------------------------
extern "C" void kernel_launch(void* const* d_in, const int* in_sizes, int n_in,
                              void* d_out, int out_size, void* d_ws, size_t ws_size,
                              hipStream_t stream) {
    const float* q    = (const float*)d_in[0];
    const float* k    = (const float*)d_in[1];
    const float* Wa1  = (const float*)d_in[2];
    const float* Wa2  = (const float*)d_in[4];
    const float* Wb1  = (const float*)d_in[6];
    const float* Wb2  = (const float*)d_in[8];
    const float* dist = (const float*)d_in[10];
    float* out = (float*)d_out;

    bf16* wsbf = (bf16*)d_ws;
    bf16* Wa1t = wsbf;                 // 512*256
    bf16* Wa2t = Wa1t + 131072;        // 256*256
    bf16* Wb1t = Wa2t + 65536;
    bf16* Wb2t = Wb1t + 131072;
    bf16* qa   = Wb2t + 65536;         // 8192*256 each
    bf16* ka   = qa + 2097152;
    bf16* qb   = ka + 2097152;
    bf16* kb   = qb + 2097152;
    // total ws ~17.6 MB; mean table reuses the Wa1t region (dead after mlp)
    float* tabg = (float*)Wa1t;        // 64*64 f32 = 16 KB << 256 KB region

    prep_weights<<<1536, 256, 0, stream>>>(Wa1, Wa2, Wb1, Wb2,
                                           Wa1t, Wa2t, Wb1t, Wb2t);

    dim3 g1(128, 1, 4), blk(256, 1, 1);
    mlp_fused<<<g1, blk, 0, stream>>>(q, k, Wa1t, Wa2t, Wb1t, Wb2t,
                                      qa, ka, qb, kb);

    gen_table<<<16, 256, 0, stream>>>(tabg);     // after mlp: Wa1t is dead

    dim3 g2(16, 32, 4);
    kuma_attn<<<g2, blk, 0, stream>>>(qa, ka, qb, kb, dist, tabg, out);
}

// Round 4
// 196.990 us; speedup vs baseline: 1.4066x; 1.0219x over previous
//
#include <hip/hip_runtime.h>
#include <hip/hip_bf16.h>
#include <math.h>

typedef __hip_bfloat16 bf16;
typedef short bf16x8 __attribute__((ext_vector_type(8)));   // 8 bf16 raw (4 VGPRs)
typedef float f32x4 __attribute__((ext_vector_type(4)));
typedef float f32x2 __attribute__((ext_vector_type(2)));

union alignas(16) Pack8 { bf16 h[8]; bf16x8 v; };

// native base-2 transcendentals (v_exp_f32 / v_log_f32 / v_rcp_f32)
#define EXP2F(x) __builtin_amdgcn_exp2f(x)
#define LOG2F(x) __builtin_amdgcn_logf(x)
#define RCPF(x)  __builtin_amdgcn_rcpf(x)

// Mean-table box: for scores in [TAB_LO, TAB_HI] (a,b in [0.533,1.502]),
// pc >= 0.596 always (corner-verified; pc unimodal in each var), so the
// output is ALWAYS the continuous mean there -> bilinear table lookup.
#define TAB_N   64
#define TAB_LO  (-0.35f)
#define TAB_HI  (1.25f)
// table stored as f32x2 pairs (T[ib],T[ib+1]) with row stride 65 entries
#define TAB_STRIDE 65

// ---------------------------------------------------------------------------
// All four weight transposes f32 -> bf16 in one dispatch.
// ---------------------------------------------------------------------------
__global__ void prep_weights(const float* __restrict__ Wa1, const float* __restrict__ Wa2,
                             const float* __restrict__ Wb1, const float* __restrict__ Wb2,
                             bf16* __restrict__ oa1, bf16* __restrict__ oa2,
                             bf16* __restrict__ ob1, bf16* __restrict__ ob2) {
    int idx = blockIdx.x * 256 + threadIdx.x;   // grid covers 393216
    if (idx < 131072) {
        int n = idx >> 9, k = idx & 511;
        oa1[idx] = __float2bfloat16(Wa1[k * 256 + n]);
    } else if (idx < 196608) {
        int i = idx - 131072; int n = i >> 8, k = i & 255;
        oa2[i] = __float2bfloat16(Wa2[k * 256 + n]);
    } else if (idx < 327680) {
        int i = idx - 196608; int n = i >> 9, k = i & 511;
        ob1[i] = __float2bfloat16(Wb1[k * 256 + n]);
    } else {
        int i = idx - 327680; int n = i >> 8, k = i & 255;
        ob2[i] = __float2bfloat16(Wb2[k * 256 + n]);
    }
}

// ---------------------------------------------------------------------------
// f32 mean (Stirling shift-4, R0/R1-validated path; err ~3e-5). Table gen only.
// ---------------------------------------------------------------------------
__device__ __forceinline__ float stirl2s(float z) {
    float iz = 1.f / z;
    return (z - 0.5f) * LOG2F(z) - 1.44269504f * z + 1.32574806f
         + iz * (0.12022651f - 0.00400749f * iz * iz);
}
__device__ __forceinline__ float sp4s(float x) {   // x(x+1)(x+2)(x+3)
    return (x * (x + 1.f)) * ((x + 2.f) * (x + 3.f));
}
__device__ float mean_f32(float sa, float sb) {
    float lw = LOG2F(1.f + EXP2F(sa * 1.44269504f));
    float lv = LOG2F(1.f + EXP2F(sb * 1.44269504f));
    lw = fminf(fmaxf(lw, 0.01442695f), 144.269504f);
    lv = fminf(fmaxf(lv, 0.01442695f), 144.269504f);
    float b = 0.69314718f * lv;
    float g = 1.44269504f / lw + 1.f;
    float gb = g + b;
    float lb2 = stirl2s(g + 4.f) + stirl2s(b + 4.f) - stirl2s(gb + 4.f)
              + LOG2F(sp4s(gb) / (sp4s(g) * sp4s(b)));
    float mean = fmaf(1.2f * b, EXP2F(lb2), -0.1f);
    return fminf(fmaxf(mean, 0.f), 1.f);
}

// Table layout: tab[(ia*TAB_STRIDE + ib)*2 + {0,1}] = (T[ia][ib], T[ia][ib+1])
__global__ void gen_table(float* __restrict__ tab) {
    int idx = blockIdx.x * 256 + threadIdx.x;
    if (idx >= TAB_N * TAB_N) return;
    int ia = idx >> 6, ib = idx & 63;
    const float step = (TAB_HI - TAB_LO) / (TAB_N - 1);
    float sa  = TAB_LO + ia * step;
    float sb  = TAB_LO + ib * step;
    int ib1 = ib < TAB_N - 1 ? ib + 1 : ib;
    float sb1 = TAB_LO + ib1 * step;
    tab[(ia * TAB_STRIDE + ib) * 2]     = mean_f32(sa, sb);
    tab[(ia * TAB_STRIDE + ib) * 2 + 1] = mean_f32(sa, sb1);
}

// ---------------------------------------------------------------------------
// Fused 2-layer MLP (round-1 form: LDS-staged, 64 rows/block, 2 barriers/kk).
// ---------------------------------------------------------------------------
__global__ __launch_bounds__(256, 2)
void mlp_fused(const float* __restrict__ q, const float* __restrict__ k,
               const bf16* __restrict__ Wa1t, const bf16* __restrict__ Wa2t,
               const bf16* __restrict__ Wb1t, const bf16* __restrict__ Wb2t,
               bf16* __restrict__ qa, bf16* __restrict__ ka,
               bf16* __restrict__ qb, bf16* __restrict__ kb) {
    const int z = blockIdx.z;
    const float* X  = (z & 1) ? k : q;
    const bf16*  W1 = (z >> 1) ? Wb1t : Wa1t;
    const bf16*  W2 = (z >> 1) ? Wb2t : Wa2t;
    bf16* Y = (z == 0) ? qa : (z == 1) ? ka : (z == 2) ? qb : kb;
    const int m0 = blockIdx.x * 64;

    __shared__ short lA[64 * 40];     // layer-1 A tile
    __shared__ short lB[256 * 40];    // W staging (both layers)
    __shared__ short lH[64 * 264];    // h: 64 rows x 256 cols (+8 pad)

    const int tid  = threadIdx.x;
    const int wave = tid >> 6, lane = tid & 63;
    const int wn = wave * 64;
    const int quad = lane >> 4, r16 = lane & 15;

    // ---- layer 1: K = 512, X is f32 (convert during staging)
    {
        f32x4 acc[4][4] = {};
        for (int kk = 0; kk < 512; kk += 32) {
            {
                int r = tid >> 2, c = (tid & 3) * 8;
                const float* p = X + (size_t)(m0 + r) * 512 + kk + c;
                Pack8 u;
#pragma unroll
                for (int j = 0; j < 8; j++) u.h[j] = __float2bfloat16(p[j]);
                *(bf16x8*)&lA[r * 40 + c] = u.v;
            }
            for (int i = tid; i < 1024; i += 256) {
                int r = i >> 2, c = (i & 3) * 8;
                *(bf16x8*)&lB[r * 40 + c] =
                    *(const bf16x8*)(W1 + (size_t)r * 512 + kk + c);
            }
            __syncthreads();
            bf16x8 af[4], bfr[4];
#pragma unroll
            for (int f = 0; f < 4; f++) {
                af[f]  = *(const bf16x8*)&lA[(f * 16 + r16) * 40 + quad * 8];
                bfr[f] = *(const bf16x8*)&lB[(wn + f * 16 + r16) * 40 + quad * 8];
            }
#pragma unroll
            for (int i = 0; i < 4; i++)
#pragma unroll
                for (int j = 0; j < 4; j++)
                    acc[i][j] = __builtin_amdgcn_mfma_f32_16x16x32_bf16(
                        af[i], bfr[j], acc[i][j], 0, 0, 0);
            __syncthreads();
        }
#pragma unroll
        for (int i = 0; i < 4; i++)
#pragma unroll
            for (int j = 0; j < 4; j++)
#pragma unroll
                for (int r = 0; r < 4; r++) {
                    float v = acc[i][j][r];
                    v = v > 0.f ? v : 0.f;
                    ((bf16*)lH)[(i * 16 + quad * 4 + r) * 264 + wn + j * 16 + r16] =
                        __float2bfloat16(v);
                }
    }
    __syncthreads();

    // ---- layer 2: K = 256, A comes from lH
    f32x4 acc2[4][4] = {};
    for (int kk = 0; kk < 256; kk += 32) {
        for (int i = tid; i < 1024; i += 256) {
            int r = i >> 2, c = (i & 3) * 8;
            *(bf16x8*)&lB[r * 40 + c] =
                *(const bf16x8*)(W2 + (size_t)r * 256 + kk + c);
        }
        __syncthreads();
        bf16x8 af[4], bfr[4];
#pragma unroll
        for (int f = 0; f < 4; f++) {
            af[f]  = *(const bf16x8*)&lH[(f * 16 + r16) * 264 + kk + quad * 8];
            bfr[f] = *(const bf16x8*)&lB[(wn + f * 16 + r16) * 40 + quad * 8];
        }
#pragma unroll
        for (int i = 0; i < 4; i++)
#pragma unroll
            for (int j = 0; j < 4; j++)
                acc2[i][j] = __builtin_amdgcn_mfma_f32_16x16x32_bf16(
                    af[i], bfr[j], acc2[i][j], 0, 0, 0);
        __syncthreads();
    }

#pragma unroll
    for (int i = 0; i < 4; i++) {
        int rbase = m0 + i * 16 + quad * 4;
#pragma unroll
        for (int j = 0; j < 4; j++) {
            int col = wn + j * 16 + r16;
#pragma unroll
            for (int r = 0; r < 4; r++) {
                float v = acc2[i][j][r];
                v = v > 0.f ? v : 0.f;
                Y[(size_t)(rbase + r) * 256 + col] = __float2bfloat16(v);
            }
        }
    }
}

// ---------------------------------------------------------------------------
// Packed f32x2 helpers.
// ---------------------------------------------------------------------------
__device__ __forceinline__ f32x2 vexp2(f32x2 x) {
    f32x2 r; r.x = EXP2F(x.x); r.y = EXP2F(x.y); return r;
}
__device__ __forceinline__ f32x2 vlog2(f32x2 x) {
    f32x2 r; r.x = LOG2F(x.x); r.y = LOG2F(x.y); return r;
}
__device__ __forceinline__ f32x2 vrcp(f32x2 x) {
    f32x2 r; r.x = RCPF(x.x); r.y = RCPF(x.y); return r;
}
__device__ __forceinline__ f32x2 vclamp(f32x2 x, float lo, float hi) {
    f32x2 r;
    r.x = fminf(fmaxf(x.x, lo), hi);
    r.y = fminf(fmaxf(x.y, lo), hi);
    return r;
}

// Exact HardKuma pair (round-1 validated). COLD fallback path only.
__device__ __noinline__ f32x2 hardkuma_slow(f32x2 la, f32x2 lb) {
    const float LOG2E = 1.44269504f;
    f32x2 lw = vlog2(1.f + vexp2(la * LOG2E));
    f32x2 lv = vlog2(1.f + vexp2(lb * LOG2E));
    lw = vclamp(lw, 0.01442695f, 144.269504f);   // a in [0.01,100]
    lv = vclamp(lv, 0.01442695f, 144.269504f);
    f32x2 b = 0.69314718f * lv;

    f32x2 t0a = vexp2(-2.48490665f * lw);        // 12^{-a}
    f32x2 t1a = vexp2(-0.08701138f * lw);        // (12/11)^{-a}
    f32x2 q0 = vexp2(b * vlog2(1.f - t0a));      // 1 - p0
    f32x2 p1 = vexp2(b * vlog2(1.f - t1a));      // P(h=1)
    f32x2 pc = q0 - p1;
    f32x2 p0 = 1.f - q0;

    f32x2 g  = 1.44269504f * vrcp(lw) + 1.f;
    f32x2 gb = g + b;
    f32x2 g2 = g + 2.f, b2 = b + 2.f, gb2 = gb + 2.f;

    f32x2 s = (g + 1.5f) * vlog2(g2) + (b + 1.5f) * vlog2(b2)
            - (gb + 1.5f) * vlog2(gb2);

    const float C1 = 0.12022459f;                // log2e/12
    const float C2 = -0.00400749f;               // -log2e/360
    f32x2 pg  = g2 * b2;
    f32x2 rr3 = vrcp(pg * gb2);
    f32x2 ig  = rr3 * (b2 * gb2);
    f32x2 ib  = rr3 * (g2 * gb2);
    f32x2 igb = rr3 * pg;
    f32x2 corr = ig  * (C1 + C2 * (ig  * ig))
               + ib  * (C1 + C2 * (ib  * ib))
               - igb * (C1 + C2 * (igb * igb));
    s += corr - 1.55964202f;                     // 0.5*log2(2pi) - 2*log2e

    f32x2 ng = g * (g + 1.f), nb = b * (b + 1.f), ngb = gb * (gb + 1.f);
    s += vlog2(ngb * vrcp(ng * nb));

    f32x2 mean = (1.2f * b) * vexp2(s) - 0.1f;
    mean = vclamp(mean, 0.f, 1.f);

    f32x2 att;
    att.x = (pc.x < 0.5f) ? ((p0.x > p1.x) ? 0.f : 1.f) : mean.x;
    att.y = (pc.y < 0.5f) ? ((p0.y > p1.y) ? 0.f : 1.f) : mean.y;
    return att;
}

// ---------------------------------------------------------------------------
// Fused score GEMMs + table-lookup HardKuma epilogue.
// Tile 128(t) x 128(s); 4 waves of 64x64 (A/B fragment reuse 4x per read);
// grid (16, 16, 4). Table gathers are ds_read_b64 (2 per element).
// ---------------------------------------------------------------------------
__global__ __launch_bounds__(256, 2)
void kuma_attn(const bf16* __restrict__ qa, const bf16* __restrict__ ka,
               const bf16* __restrict__ qb, const bf16* __restrict__ kb,
               const float* __restrict__ dist_emb, const float* __restrict__ tabg,
               float* __restrict__ out) {
    const int bidx = blockIdx.z;
    const int t0 = blockIdx.x * 128;
    const int s0 = blockIdx.y * 128;

    __shared__ short lQa[128 * 40], lQb[128 * 40];
    __shared__ short lKa[128 * 40], lKb[128 * 40];
    __shared__ float sDist[23];
    __shared__ float sTab[TAB_N * TAB_STRIDE * 2];   // 33.3 KB packed-pair table

    const int tid = threadIdx.x;
    if (tid < 23) sDist[tid] = dist_emb[tid];
    for (int i = tid; i < (TAB_N * TAB_STRIDE * 2) / 4; i += 256)
        ((f32x4*)sTab)[i] = ((const f32x4*)tabg)[i];
    // first k-loop barrier covers sDist/sTab visibility (used only in epilogue)

    const int wave = tid >> 6, lane = tid & 63;
    const int wm = (wave >> 1) * 64, wn = (wave & 1) * 64;
    const int quad = lane >> 4, r16 = lane & 15;
    const size_t base = (size_t)bidx * 2048 * 256;

    f32x4 accA[4][4] = {};
    f32x4 accB[4][4] = {};

    const int r0 = tid >> 2, c0 = (tid & 3) * 8;          // rows 0..63
    const int r1 = r0 + 64,  c1 = c0;                     // rows 64..127

    for (int kk = 0; kk < 256; kk += 32) {
        {
            size_t gq0 = base + (size_t)(t0 + r0) * 256 + kk + c0;
            size_t gq1 = base + (size_t)(t0 + r1) * 256 + kk + c1;
            *(bf16x8*)&lQa[r0 * 40 + c0] = *(const bf16x8*)(qa + gq0);
            *(bf16x8*)&lQb[r0 * 40 + c0] = *(const bf16x8*)(qb + gq0);
            *(bf16x8*)&lQa[r1 * 40 + c1] = *(const bf16x8*)(qa + gq1);
            *(bf16x8*)&lQb[r1 * 40 + c1] = *(const bf16x8*)(qb + gq1);
            size_t gk0 = base + (size_t)(s0 + r0) * 256 + kk + c0;
            size_t gk1 = base + (size_t)(s0 + r1) * 256 + kk + c1;
            *(bf16x8*)&lKa[r0 * 40 + c0] = *(const bf16x8*)(ka + gk0);
            *(bf16x8*)&lKb[r0 * 40 + c0] = *(const bf16x8*)(kb + gk0);
            *(bf16x8*)&lKa[r1 * 40 + c1] = *(const bf16x8*)(ka + gk1);
            *(bf16x8*)&lKb[r1 * 40 + c1] = *(const bf16x8*)(kb + gk1);
        }
        __syncthreads();
        bf16x8 aA[4], aB[4], bA[4], bB[4];
#pragma unroll
        for (int f = 0; f < 4; f++) {
            int ar = (wm + f * 16 + r16) * 40 + quad * 8;
            aA[f] = *(const bf16x8*)&lQa[ar];
            aB[f] = *(const bf16x8*)&lQb[ar];
            int br = (wn + f * 16 + r16) * 40 + quad * 8;
            bA[f] = *(const bf16x8*)&lKa[br];
            bB[f] = *(const bf16x8*)&lKb[br];
        }
#pragma unroll
        for (int i = 0; i < 4; i++)
#pragma unroll
            for (int j = 0; j < 4; j++) {
                accA[i][j] = __builtin_amdgcn_mfma_f32_16x16x32_bf16(
                    aA[i], bA[j], accA[i][j], 0, 0, 0);
                accB[i][j] = __builtin_amdgcn_mfma_f32_16x16x32_bf16(
                    aB[i], bB[j], accB[i][j], 0, 0, 0);
            }
        __syncthreads();
    }

    // Epilogue: bilinear mean-table lookup; b-interp pairs come packed from
    // one ds_read_b64 each. __any-guarded exact fallback for out-of-box lanes.
    const float SCALE = (TAB_N - 1) / (TAB_HI - TAB_LO);   // 39.375
#pragma unroll
    for (int i = 0; i < 4; i++) {
#pragma unroll
        for (int j = 0; j < 4; j++) {
            int s = s0 + wn + j * 16 + r16;
#pragma unroll
            for (int rr = 0; rr < 2; rr++) {
                int t = t0 + wm + i * 16 + quad * 4 + rr * 2;
                int d0 = s - t;
                int d1 = d0 - 1;
                d0 = d0 < -11 ? -11 : (d0 > 11 ? 11 : d0);
                d1 = d1 < -11 ? -11 : (d1 > 11 ? 11 : d1);
                float rd0 = sDist[d0 + 11];
                float rd1 = sDist[d1 + 11];
                f32x2 la  = { accA[i][j][rr * 2] + rd0, accA[i][j][rr * 2 + 1] + rd1 };
                f32x2 lbv = { accB[i][j][rr * 2] + rd0, accB[i][j][rr * 2 + 1] + rd1 };

                float mn = fminf(fminf(la.x, la.y), fminf(lbv.x, lbv.y));
                float mx = fmaxf(fmaxf(la.x, la.y), fmaxf(lbv.x, lbv.y));

                f32x2 u = vclamp((la  - TAB_LO) * SCALE, 0.f, (float)(TAB_N - 1));
                f32x2 v = vclamp((lbv - TAB_LO) * SCALE, 0.f, (float)(TAB_N - 1));
                int ia0 = (int)u.x; ia0 = ia0 > TAB_N - 2 ? TAB_N - 2 : ia0;
                int ia1 = (int)u.y; ia1 = ia1 > TAB_N - 2 ? TAB_N - 2 : ia1;
                int ib0 = (int)v.x; ib0 = ib0 > TAB_N - 2 ? TAB_N - 2 : ib0;
                int ib1 = (int)v.y; ib1 = ib1 > TAB_N - 2 ? TAB_N - 2 : ib1;
                f32x2 fa = { u.x - (float)ia0, u.y - (float)ia1 };
                f32x2 fb = { v.x - (float)ib0, v.y - (float)ib1 };
                // element x: rows ia0, ia0+1; element y: rows ia1, ia1+1
                int o0 = (ia0 * TAB_STRIDE + ib0) * 2;
                int o1 = (ia1 * TAB_STRIDE + ib1) * 2;
                f32x2 e0r0 = *(const f32x2*)&sTab[o0];
                f32x2 e0r1 = *(const f32x2*)&sTab[o0 + TAB_STRIDE * 2];
                f32x2 e1r0 = *(const f32x2*)&sTab[o1];
                f32x2 e1r1 = *(const f32x2*)&sTab[o1 + TAB_STRIDE * 2];
                f32x2 m0 = { e0r0.x + fb.x * (e0r0.y - e0r0.x),
                             e1r0.x + fb.y * (e1r0.y - e1r0.x) };
                f32x2 m1 = { e0r1.x + fb.x * (e0r1.y - e0r1.x),
                             e1r1.x + fb.y * (e1r1.y - e1r1.x) };
                f32x2 att = m0 + fa * (m1 - m0);

                bool oob = (mn < TAB_LO) | (mx > TAB_HI);
                if (__builtin_expect(__any(oob), 0)) {
                    f32x2 ex = hardkuma_slow(la, lbv);
                    if (oob) att = ex;
                }

                out[((size_t)bidx * 2048 + t) * 2048 + s] = att.x;
                out[((size_t)bidx * 2048 + t + 1) * 2048 + s] = att.y;
            }
        }
    }
}

// ---------------------------------------------------------------------------
extern "C" void kernel_launch(void* const* d_in, const int* in_sizes, int n_in,
                              void* d_out, int out_size, void* d_ws, size_t ws_size,
                              hipStream_t stream) {
    const float* q    = (const float*)d_in[0];
    const float* k    = (const float*)d_in[1];
    const float* Wa1  = (const float*)d_in[2];
    const float* Wa2  = (const float*)d_in[4];
    const float* Wb1  = (const float*)d_in[6];
    const float* Wb2  = (const float*)d_in[8];
    const float* dist = (const float*)d_in[10];
    float* out = (float*)d_out;

    bf16* wsbf = (bf16*)d_ws;
    bf16* Wa1t = wsbf;                 // 512*256
    bf16* Wa2t = Wa1t + 131072;        // 256*256
    bf16* Wb1t = Wa2t + 65536;
    bf16* Wb2t = Wb1t + 131072;
    bf16* qa   = Wb2t + 65536;         // 8192*256 each
    bf16* ka   = qa + 2097152;
    bf16* qb   = ka + 2097152;
    bf16* kb   = qb + 2097152;
    // total ws ~17.6 MB; mean table reuses the Wa1t region (dead after mlp)
    float* tabg = (float*)Wa1t;        // 64*65*2 f32 = 33.3 KB << 256 KB region

    prep_weights<<<1536, 256, 0, stream>>>(Wa1, Wa2, Wb1, Wb2,
                                           Wa1t, Wa2t, Wb1t, Wb2t);

    dim3 g1(128, 1, 4), blk(256, 1, 1);
    mlp_fused<<<g1, blk, 0, stream>>>(q, k, Wa1t, Wa2t, Wb1t, Wb2t,
                                      qa, ka, qb, kb);

    gen_table<<<16, 256, 0, stream>>>(tabg);     // after mlp: Wa1t is dead

    dim3 g2(16, 16, 4);
    kuma_attn<<<g2, blk, 0, stream>>>(qa, ka, qb, kb, dist, tabg, out);
}